// Round 2
// 505.592 us; speedup vs baseline: 1.0592x; 1.0592x over previous
//
#include <hip/hip_runtime.h>
#include <math.h>

#define MTOT 65536   // B*T
#define DD   128
#define KK   1024
#define BETA 0.25f
#define TM   64      // rows per k_main block
#define NCH  64      // codes per chunk

typedef __attribute__((ext_vector_type(8))) short short8;
typedef __attribute__((ext_vector_type(4))) float float4v;

__device__ __forceinline__ unsigned bf16_rne(float x) {
    unsigned u = __float_as_uint(x);
    return (u + 0x7fffu + ((u >> 16) & 1u)) >> 16;
}

__device__ __forceinline__ void gload_lds16(const void* g, void* l) {
    __builtin_amdgcn_global_load_lds(
        (const __attribute__((address_space(1))) unsigned int*)g,
        (__attribute__((address_space(3))) unsigned int*)l, 16, 0, 0);
}

// --------- K0: codebook -> bf16 hi/lo PRE-SWIZZLED (for global_load_lds) ----
// Global layout per part: code row = 256 B; within a row, 16B chunk j stored
// at (j*16) ^ ((code&7)<<4). k_main's linear LDS staging then yields a
// bank-conflict-free swizzled tile read back with the same XOR.
__global__ void k_norms(const float* __restrict__ e, ushort* __restrict__ bp,
                        float* __restrict__ nef, float* __restrict__ inef,
                        float* __restrict__ loss) {
    const int gw = blockIdx.x * 4 + (threadIdx.x >> 6);
    const int lane = threadIdx.x & 63;
    char* hb = (char*)bp;
    char* lb = hb + 262144;                   // lo part after hi part
    const int sub = lane & 3;
    for (int code = gw; code < KK; code += 16) {
        float2 ev = ((const float2*)(e + (size_t)code * DD))[lane];
        unsigned h0 = bf16_rne(ev.x), h1 = bf16_rne(ev.y);
        float l0f = ev.x - __uint_as_float(h0 << 16);
        float l1f = ev.y - __uint_as_float(h1 << 16);
        ushort2 hv; hv.x = (ushort)h0; hv.y = (ushort)h1;
        ushort2 lv; lv.x = (ushort)bf16_rne(l0f); lv.y = (ushort)bf16_rne(l1f);
        int sw = (((lane >> 2) * 16) ^ ((code & 7) << 4)) + sub * 4;
        *(ushort2*)(hb + code * 256 + sw) = hv;
        *(ushort2*)(lb + code * 256 + sw) = lv;
        float s = ev.x * ev.x + ev.y * ev.y;
        #pragma unroll
        for (int off = 32; off; off >>= 1) s += __shfl_down(s, off, 64);
        if (lane == 0) { nef[code] = s; inef[code] = 1.0f / sqrtf(s); }
    }
    if (blockIdx.x == 0 && threadIdx.x == 0) *loss = 0.0f;
}

// --------- K1: A-in-registers split-bf16 MFMA + sim write + top-2 ----------
__launch_bounds__(256, 2)
__global__ void k_main(const float* __restrict__ z, float* __restrict__ sim,
                       const ushort* __restrict__ bpre,
                       const float* __restrict__ nef, const float* __restrict__ inef,
                       unsigned* __restrict__ cand) {
    // double-buffered B chunk: [buf][hi 16KB | lo 16KB] = 64 KB
    __shared__ __align__(16) ushort Bs[2 * 16384];
    __shared__ float nzv[TM], inzv[TM];

    const int t = threadIdx.x;
    const int w = t >> 6, lane = t & 63, cl = lane & 15, q = lane >> 4;
    const int mh = (w & 1) * 32, nh = (w >> 1) * 32;
    const int r0 = blockIdx.x * TM;

    auto STAGE = [&](int buf, int ch2) {
        const char* gb = (const char*)bpre + (size_t)ch2 * 16384;
        #pragma unroll
        for (int i = 0; i < 8; ++i) {
            int slot = i * 256 + t;                       // 0..2047, 16B each
            int goff = slot * 16 + ((slot >= 1024) ? 245760 : 0);  // lo part adj
            gload_lds16(gb + goff,
                        (char*)Bs + buf * 32768 + (i * 256 + (t & 0xFFC0)) * 16);
        }
    };

    // issue chunk-0 B staging first so it overlaps the A load/convert
    STAGE(0, 0);

    // ---- A: load z directly, split to bf16 hi/lo in regs, accumulate |z|^2 -
    short8 afh[2][4], afl[2][4];
    float pn0 = 0.0f, pn1 = 0.0f;
    const char* zb = (const char*)z;
    #pragma unroll
    for (int mt = 0; mt < 2; ++mt) {
        const char* rp = zb + (size_t)(r0 + mh + mt * 16 + cl) * 512;
        #pragma unroll
        for (int s = 0; s < 4; ++s) {
            float4v f0 = *(const float4v*)(rp + s * 128 + q * 32);
            float4v f1 = *(const float4v*)(rp + s * 128 + q * 32 + 16);
            short8 h, l;
            float ps = 0.0f;
            #pragma unroll
            for (int j = 0; j < 4; ++j) {
                float fx = f0[j];
                unsigned hu = bf16_rne(fx);
                h[j] = (short)hu;
                l[j] = (short)bf16_rne(fx - __uint_as_float(hu << 16));
                ps += fx * fx;
                float fy = f1[j];
                unsigned hw2 = bf16_rne(fy);
                h[j + 4] = (short)hw2;
                l[j + 4] = (short)bf16_rne(fy - __uint_as_float(hw2 << 16));
                ps += fy * fy;
            }
            afh[mt][s] = h; afl[mt][s] = l;
            if (mt == 0) pn0 += ps; else pn1 += ps;
        }
    }
    pn0 += __shfl_xor(pn0, 16, 64); pn0 += __shfl_xor(pn0, 32, 64);
    pn1 += __shfl_xor(pn1, 16, 64); pn1 += __shfl_xor(pn1, 32, 64);
    if (q == 0) {
        nzv[mh + cl]      = pn0; inzv[mh + cl]      = 1.0f / sqrtf(pn0);
        nzv[mh + 16 + cl] = pn1; inzv[mh + 16 + cl] = 1.0f / sqrtf(pn1);
    }
    __syncthreads();   // nzv ready; chunk-0 stage drained (vmcnt(0) at barrier)

    float nzr[8], inzr[8];
    #pragma unroll
    for (int mt = 0; mt < 2; ++mt)
        #pragma unroll
        for (int r = 0; r < 4; ++r) {
            int rl = mh + mt * 16 + q * 4 + r;
            nzr[mt * 4 + r] = nzv[rl]; inzr[mt * 4 + r] = inzv[rl];
        }

    float b1v[8], b2v[8]; int b1i[8], b2i[8];
    #pragma unroll
    for (int s = 0; s < 8; ++s) { b1v[s] = 3.4e38f; b2v[s] = 3.4e38f; b1i[s] = 0; b2i[s] = 0; }

    const int swz = (cl & 7) << 4;
    for (int ch = 0; ch < 16; ++ch) {
        const int c0 = ch * NCH;
        const char* Bb = (const char*)Bs + (ch & 1) * 32768;
        if (ch < 15) STAGE((ch + 1) & 1, ch + 1);   // prefetch next chunk

        float nec[2], inec[2];
        #pragma unroll
        for (int nt = 0; nt < 2; ++nt) {
            int c = c0 + nh + nt * 16 + cl;
            nec[nt] = nef[c]; inec[nt] = inef[c];
        }

        float4v acc[2][2];
        #pragma unroll
        for (int mt = 0; mt < 2; ++mt)
            #pragma unroll
            for (int nt = 0; nt < 2; ++nt) acc[mt][nt] = (float4v)(0.0f);

        // pass 0: Ah*Bh — load Bh frags and HOLD them for pass 2
        short8 bh0[4], bh1[4];
        #pragma unroll
        for (int s = 0; s < 4; ++s) {
            const int ko = (s * 64 + q * 16) ^ swz;
            bh0[s] = *(const short8*)(Bb + (nh + cl) * 256 + ko);
            bh1[s] = *(const short8*)(Bb + (nh + 16 + cl) * 256 + ko);
            acc[0][0] = __builtin_amdgcn_mfma_f32_16x16x32_bf16(afh[0][s], bh0[s], acc[0][0], 0, 0, 0);
            acc[0][1] = __builtin_amdgcn_mfma_f32_16x16x32_bf16(afh[0][s], bh1[s], acc[0][1], 0, 0, 0);
            acc[1][0] = __builtin_amdgcn_mfma_f32_16x16x32_bf16(afh[1][s], bh0[s], acc[1][0], 0, 0, 0);
            acc[1][1] = __builtin_amdgcn_mfma_f32_16x16x32_bf16(afh[1][s], bh1[s], acc[1][1], 0, 0, 0);
        }
        // pass 1: Ah*Bl
        #pragma unroll
        for (int s = 0; s < 4; ++s) {
            const int ko = (s * 64 + q * 16) ^ swz;
            short8 bl0 = *(const short8*)(Bb + 16384 + (nh + cl) * 256 + ko);
            short8 bl1 = *(const short8*)(Bb + 16384 + (nh + 16 + cl) * 256 + ko);
            acc[0][0] = __builtin_amdgcn_mfma_f32_16x16x32_bf16(afh[0][s], bl0, acc[0][0], 0, 0, 0);
            acc[0][1] = __builtin_amdgcn_mfma_f32_16x16x32_bf16(afh[0][s], bl1, acc[0][1], 0, 0, 0);
            acc[1][0] = __builtin_amdgcn_mfma_f32_16x16x32_bf16(afh[1][s], bl0, acc[1][0], 0, 0, 0);
            acc[1][1] = __builtin_amdgcn_mfma_f32_16x16x32_bf16(afh[1][s], bl1, acc[1][1], 0, 0, 0);
        }
        // pass 2: Al*Bh (Bh frags still in registers — no LDS reads)
        #pragma unroll
        for (int s = 0; s < 4; ++s) {
            acc[0][0] = __builtin_amdgcn_mfma_f32_16x16x32_bf16(afl[0][s], bh0[s], acc[0][0], 0, 0, 0);
            acc[0][1] = __builtin_amdgcn_mfma_f32_16x16x32_bf16(afl[0][s], bh1[s], acc[0][1], 0, 0, 0);
            acc[1][0] = __builtin_amdgcn_mfma_f32_16x16x32_bf16(afl[1][s], bh0[s], acc[1][0], 0, 0, 0);
            acc[1][1] = __builtin_amdgcn_mfma_f32_16x16x32_bf16(afl[1][s], bh1[s], acc[1][1], 0, 0, 0);
        }

        __syncthreads();   // drains prefetch vmcnt; all waves done reading Bb

        // epilogue: sim write + per-lane top-2 (registers only, overlaps next chunk)
        #pragma unroll
        for (int mt = 0; mt < 2; ++mt)
            #pragma unroll
            for (int r = 0; r < 4; ++r) {
                const int slot = mt * 4 + r;
                const size_t rowg = (size_t)(r0 + mh + mt * 16 + q * 4 + r);
                #pragma unroll
                for (int nt = 0; nt < 2; ++nt) {
                    float dot = acc[mt][nt][r];
                    int col = c0 + nh + nt * 16 + cl;
                    sim[rowg * KK + col] = dot * inzr[slot] * inec[nt];
                    float dist = fmaf(-2.0f, dot, nzr[slot] + nec[nt]);
                    if (dist < b1v[slot]) {
                        b2v[slot] = b1v[slot]; b2i[slot] = b1i[slot];
                        b1v[slot] = dist;      b1i[slot] = col;
                    } else if (dist < b2v[slot]) {
                        b2v[slot] = dist; b2i[slot] = col;
                    }
                }
            }
    }

    // cross-lane top-2 merge per row (reuse LDS: buf0 as floats, buf1 as ints)
    float* redv = (float*)Bs;            // [64 rows][32 entries][2]
    int*   redi = (int*)(Bs + 16384);
    #pragma unroll
    for (int mt = 0; mt < 2; ++mt)
        #pragma unroll
        for (int r = 0; r < 4; ++r) {
            int slot = mt * 4 + r;
            int rl = mh + mt * 16 + q * 4 + r;
            int ei = rl * 64 + ((w >> 1) * 16 + cl) * 2;
            redv[ei] = b1v[slot]; redv[ei + 1] = b2v[slot];
            redi[ei] = b1i[slot]; redi[ei + 1] = b2i[slot];
        }
    __syncthreads();
    if (t < TM) {
        float B1v = 3.4e38f, B2v = 3.4e38f; int B1i = 0x7fffffff, B2i = 0x7fffffff;
        for (int j = 0; j < 64; ++j) {
            float v = redv[t * 64 + j]; int ii = redi[t * 64 + j];
            if (v < B1v || (v == B1v && ii < B1i)) { B2v = B1v; B2i = B1i; B1v = v; B1i = ii; }
            else if (v < B2v || (v == B2v && ii < B2i)) { B2v = v; B2i = ii; }
        }
        cand[r0 + t] = (unsigned)B1i | ((unsigned)B2i << 16);
    }
}

// --------- K2: exact fp32 re-rank of top-2, z_q gather, ids->float, loss ----
__global__ void k_finish(const float* __restrict__ z, const float* __restrict__ e,
                         float* __restrict__ zq, float* __restrict__ idsf,
                         float* __restrict__ loss) {
    const int t = threadIdx.x, w = t >> 6, lane = t & 63;
    const int rbase = blockIdx.x * 64 + w * 16;
    float wsum = 0.0f;
    for (int i = 0; i < 16; ++i) {
        int row = rbase + i;
        unsigned pk = ((const unsigned*)idsf)[row];
        int c1 = (int)(pk & 0xffffu), c2 = (int)(pk >> 16);
        float2 zv = ((const float2*)(z + (size_t)row * DD))[lane];
        float2 e1 = ((const float2*)(e + (size_t)c1 * DD))[lane];
        float2 e2 = ((const float2*)(e + (size_t)c2 * DD))[lane];
        float v0 = zv.x * zv.x + zv.y * zv.y;   // |z|^2
        float v1 = zv.x * e1.x + zv.y * e1.y;   // z.e1
        float v2 = zv.x * e2.x + zv.y * e2.y;   // z.e2
        float v3 = e1.x * e1.x + e1.y * e1.y;   // |e1|^2
        float v4 = e2.x * e2.x + e2.y * e2.y;   // |e2|^2
        #pragma unroll
        for (int off = 32; off; off >>= 1) {
            v0 += __shfl_down(v0, off, 64);
            v1 += __shfl_down(v1, off, 64);
            v2 += __shfl_down(v2, off, 64);
            v3 += __shfl_down(v3, off, 64);
            v4 += __shfl_down(v4, off, 64);
        }
        int choice = 0; float ssq = 0.0f;
        if (lane == 0) {
            float d1 = fmaf(-2.0f, v1, v0 + v3);
            float d2 = fmaf(-2.0f, v2, v0 + v4);
            choice = (d2 < d1 || (d2 == d1 && c2 < c1)) ? 1 : 0;
            ssq = choice ? d2 : d1;             // = |z - e*|^2
        }
        choice = __shfl(choice, 0, 64);
        float2 es; es.x = choice ? e2.x : e1.x; es.y = choice ? e2.y : e1.y;
        int cs = choice ? c2 : c1;
        ((float2*)(zq + (size_t)row * DD))[lane] = es;
        if (lane == 0) {
            wsum += sqrtf(fmaxf(ssq, 0.0f));
            idsf[row] = (float)cs;
        }
    }
    __shared__ float bs[4];
    if (lane == 0) bs[w] = wsum;
    __syncthreads();
    if (t == 0)
        atomicAdd(loss, (bs[0] + bs[1] + bs[2] + bs[3]) * ((1.0f + BETA) / (float)MTOT));
}

// ---------------- launcher --------------------------------------------------
extern "C" void kernel_launch(void* const* d_in, const int* in_sizes, int n_in,
                              void* d_out, int out_size, void* d_ws, size_t ws_size,
                              hipStream_t stream) {
    const float* z = (const float*)d_in[0];
    const float* e = (const float*)d_in[1];
    float* out  = (float*)d_out;
    float* zq   = out;                          // [MTOT*DD]
    float* sim  = out + (size_t)MTOT * DD;      // [MTOT*KK]
    float* idsf = sim + (size_t)MTOT * KK;      // [MTOT]
    float* loss = idsf + MTOT;                  // [1]

    // codebook bf16 hi/lo (pre-swizzled) + norms parked in z_q region
    ushort* bpre = (ushort*)zq;                 // hi: [0,262144)B, lo: [262144,524288)B
    float*  nef  = zq + 131072;                 // after both parts
    float*  inef = nef + 1024;

    k_norms <<<4,         256, 0, stream>>>(e, bpre, nef, inef, loss);
    k_main  <<<MTOT / TM, 256, 0, stream>>>(z, sim, bpre, nef, inef, (unsigned*)idsf);
    k_finish<<<MTOT / 64, 256, 0, stream>>>(z, e, zq, idsf, loss);
}

// Round 3
// 455.746 us; speedup vs baseline: 1.1751x; 1.1094x over previous
//
#include <hip/hip_runtime.h>
#include <math.h>

#define MTOT 65536   // B*T
#define DD   128
#define KK   1024
#define BETA 0.25f
#define TM   64      // rows per k_main block
#define NCH  64      // codes per chunk

typedef __attribute__((ext_vector_type(8))) short short8;
typedef __attribute__((ext_vector_type(4))) float float4v;

__device__ __forceinline__ unsigned bf16_rne(float x) {
    unsigned u = __float_as_uint(x);
    return (u + 0x7fffu + ((u >> 16) & 1u)) >> 16;
}

__device__ __forceinline__ void gload_lds16(const void* g, void* l) {
    __builtin_amdgcn_global_load_lds(
        (const __attribute__((address_space(1))) unsigned int*)g,
        (__attribute__((address_space(3))) unsigned int*)l, 16, 0, 0);
}

// --------- K0: codebook -> bf16 hi/lo PRE-SWIZZLED (for global_load_lds) ----
// Grid widened to 64 blocks (256 waves): k_norms is on the critical path
// (k_main can't start until bpre is ready); at grid=4 it was ~25-30 us of
// serial per-wave work, now ~4 codes/wave.
__global__ void k_norms(const float* __restrict__ e, ushort* __restrict__ bp,
                        float* __restrict__ nef, float* __restrict__ inef,
                        float* __restrict__ loss) {
    const int gw = blockIdx.x * 4 + (threadIdx.x >> 6);
    const int lane = threadIdx.x & 63;
    char* hb = (char*)bp;
    char* lb = hb + 262144;                   // lo part after hi part
    const int sub = lane & 3;
    for (int code = gw; code < KK; code += 256) {
        float2 ev = ((const float2*)(e + (size_t)code * DD))[lane];
        unsigned h0 = bf16_rne(ev.x), h1 = bf16_rne(ev.y);
        float l0f = ev.x - __uint_as_float(h0 << 16);
        float l1f = ev.y - __uint_as_float(h1 << 16);
        ushort2 hv; hv.x = (ushort)h0; hv.y = (ushort)h1;
        ushort2 lv; lv.x = (ushort)bf16_rne(l0f); lv.y = (ushort)bf16_rne(l1f);
        int sw = (((lane >> 2) * 16) ^ ((code & 7) << 4)) + sub * 4;
        *(ushort2*)(hb + code * 256 + sw) = hv;
        *(ushort2*)(lb + code * 256 + sw) = lv;
        float s = ev.x * ev.x + ev.y * ev.y;
        #pragma unroll
        for (int off = 32; off; off >>= 1) s += __shfl_down(s, off, 64);
        if (lane == 0) { nef[code] = s; inef[code] = 1.0f / sqrtf(s); }
    }
    if (blockIdx.x == 0 && threadIdx.x == 0) *loss = 0.0f;
}

// --------- K1: A-in-registers split-bf16 MFMA + sim + top-2 + fused finish --
__launch_bounds__(256, 2)
__global__ void k_main(const float* __restrict__ z, float* __restrict__ sim,
                       const ushort* __restrict__ bpre,
                       const float* __restrict__ nef, const float* __restrict__ inef,
                       const float* __restrict__ e, float* __restrict__ zq,
                       float* __restrict__ idsf, float* __restrict__ loss) {
    // double-buffered B chunk: [buf][hi 16KB | lo 16KB] = 64 KB
    __shared__ __align__(16) ushort Bs[2 * 16384];
    __shared__ float nzv[TM], inzv[TM];
    __shared__ unsigned candL[TM];
    __shared__ float bs[4];

    const int t = threadIdx.x;
    const int w = t >> 6, lane = t & 63, cl = lane & 15, q = lane >> 4;
    const int mh = (w & 1) * 32, nh = (w >> 1) * 32;
    const int r0 = blockIdx.x * TM;

    auto STAGE = [&](int buf, int ch2) {
        const char* gb = (const char*)bpre + (size_t)ch2 * 16384;
        #pragma unroll
        for (int i = 0; i < 8; ++i) {
            int slot = i * 256 + t;                       // 0..2047, 16B each
            int goff = slot * 16 + ((slot >= 1024) ? 245760 : 0);  // lo part adj
            gload_lds16(gb + goff,
                        (char*)Bs + buf * 32768 + (i * 256 + (t & 0xFFC0)) * 16);
        }
    };

    // issue chunk-0 B staging first so it overlaps the A load/convert
    STAGE(0, 0);

    // ---- A: load z directly, split to bf16 hi/lo in regs, accumulate |z|^2 -
    short8 afh[2][4], afl[2][4];
    float pn0 = 0.0f, pn1 = 0.0f;
    const char* zb = (const char*)z;
    #pragma unroll
    for (int mt = 0; mt < 2; ++mt) {
        const char* rp = zb + (size_t)(r0 + mh + mt * 16 + cl) * 512;
        #pragma unroll
        for (int s = 0; s < 4; ++s) {
            float4v f0 = *(const float4v*)(rp + s * 128 + q * 32);
            float4v f1 = *(const float4v*)(rp + s * 128 + q * 32 + 16);
            short8 h, l;
            float ps = 0.0f;
            #pragma unroll
            for (int j = 0; j < 4; ++j) {
                float fx = f0[j];
                unsigned hu = bf16_rne(fx);
                h[j] = (short)hu;
                l[j] = (short)bf16_rne(fx - __uint_as_float(hu << 16));
                ps += fx * fx;
                float fy = f1[j];
                unsigned hw2 = bf16_rne(fy);
                h[j + 4] = (short)hw2;
                l[j + 4] = (short)bf16_rne(fy - __uint_as_float(hw2 << 16));
                ps += fy * fy;
            }
            afh[mt][s] = h; afl[mt][s] = l;
            if (mt == 0) pn0 += ps; else pn1 += ps;
        }
    }
    pn0 += __shfl_xor(pn0, 16, 64); pn0 += __shfl_xor(pn0, 32, 64);
    pn1 += __shfl_xor(pn1, 16, 64); pn1 += __shfl_xor(pn1, 32, 64);
    if (q == 0) {
        nzv[mh + cl]      = pn0; inzv[mh + cl]      = 1.0f / sqrtf(pn0);
        nzv[mh + 16 + cl] = pn1; inzv[mh + 16 + cl] = 1.0f / sqrtf(pn1);
    }
    __syncthreads();   // nzv ready; chunk-0 stage drained (vmcnt(0) at barrier)

    float nzr[8], inzr[8];
    #pragma unroll
    for (int mt = 0; mt < 2; ++mt)
        #pragma unroll
        for (int r = 0; r < 4; ++r) {
            int rl = mh + mt * 16 + q * 4 + r;
            nzr[mt * 4 + r] = nzv[rl]; inzr[mt * 4 + r] = inzv[rl];
        }

    float b1v[8], b2v[8]; int b1i[8], b2i[8];
    #pragma unroll
    for (int s = 0; s < 8; ++s) { b1v[s] = 3.4e38f; b2v[s] = 3.4e38f; b1i[s] = 0; b2i[s] = 0; }

    const int swz = (cl & 7) << 4;
    for (int ch = 0; ch < 16; ++ch) {
        const int c0 = ch * NCH;
        const char* Bb = (const char*)Bs + (ch & 1) * 32768;
        if (ch < 15) STAGE((ch + 1) & 1, ch + 1);   // prefetch next chunk

        float nec[2], inec[2];
        #pragma unroll
        for (int nt = 0; nt < 2; ++nt) {
            int c = c0 + nh + nt * 16 + cl;
            nec[nt] = nef[c]; inec[nt] = inef[c];
        }

        float4v acc[2][2];
        #pragma unroll
        for (int mt = 0; mt < 2; ++mt)
            #pragma unroll
            for (int nt = 0; nt < 2; ++nt) acc[mt][nt] = (float4v)(0.0f);

        // pass 0: Ah*Bh — load Bh frags and HOLD them for pass 2
        short8 bh0[4], bh1[4];
        #pragma unroll
        for (int s = 0; s < 4; ++s) {
            const int ko = (s * 64 + q * 16) ^ swz;
            bh0[s] = *(const short8*)(Bb + (nh + cl) * 256 + ko);
            bh1[s] = *(const short8*)(Bb + (nh + 16 + cl) * 256 + ko);
            acc[0][0] = __builtin_amdgcn_mfma_f32_16x16x32_bf16(afh[0][s], bh0[s], acc[0][0], 0, 0, 0);
            acc[0][1] = __builtin_amdgcn_mfma_f32_16x16x32_bf16(afh[0][s], bh1[s], acc[0][1], 0, 0, 0);
            acc[1][0] = __builtin_amdgcn_mfma_f32_16x16x32_bf16(afh[1][s], bh0[s], acc[1][0], 0, 0, 0);
            acc[1][1] = __builtin_amdgcn_mfma_f32_16x16x32_bf16(afh[1][s], bh1[s], acc[1][1], 0, 0, 0);
        }
        // pass 1: Ah*Bl
        #pragma unroll
        for (int s = 0; s < 4; ++s) {
            const int ko = (s * 64 + q * 16) ^ swz;
            short8 bl0 = *(const short8*)(Bb + 16384 + (nh + cl) * 256 + ko);
            short8 bl1 = *(const short8*)(Bb + 16384 + (nh + 16 + cl) * 256 + ko);
            acc[0][0] = __builtin_amdgcn_mfma_f32_16x16x32_bf16(afh[0][s], bl0, acc[0][0], 0, 0, 0);
            acc[0][1] = __builtin_amdgcn_mfma_f32_16x16x32_bf16(afh[0][s], bl1, acc[0][1], 0, 0, 0);
            acc[1][0] = __builtin_amdgcn_mfma_f32_16x16x32_bf16(afh[1][s], bl0, acc[1][0], 0, 0, 0);
            acc[1][1] = __builtin_amdgcn_mfma_f32_16x16x32_bf16(afh[1][s], bl1, acc[1][1], 0, 0, 0);
        }
        // pass 2: Al*Bh (Bh frags still in registers — no LDS reads)
        #pragma unroll
        for (int s = 0; s < 4; ++s) {
            acc[0][0] = __builtin_amdgcn_mfma_f32_16x16x32_bf16(afl[0][s], bh0[s], acc[0][0], 0, 0, 0);
            acc[0][1] = __builtin_amdgcn_mfma_f32_16x16x32_bf16(afl[0][s], bh1[s], acc[0][1], 0, 0, 0);
            acc[1][0] = __builtin_amdgcn_mfma_f32_16x16x32_bf16(afl[1][s], bh0[s], acc[1][0], 0, 0, 0);
            acc[1][1] = __builtin_amdgcn_mfma_f32_16x16x32_bf16(afl[1][s], bh1[s], acc[1][1], 0, 0, 0);
        }

        __syncthreads();   // drains prefetch vmcnt; all waves done reading Bb

        // epilogue: sim write + per-lane top-2 (registers only, overlaps next chunk)
        #pragma unroll
        for (int mt = 0; mt < 2; ++mt)
            #pragma unroll
            for (int r = 0; r < 4; ++r) {
                const int slot = mt * 4 + r;
                const size_t rowg = (size_t)(r0 + mh + mt * 16 + q * 4 + r);
                #pragma unroll
                for (int nt = 0; nt < 2; ++nt) {
                    float dot = acc[mt][nt][r];
                    int col = c0 + nh + nt * 16 + cl;
                    sim[rowg * KK + col] = dot * inzr[slot] * inec[nt];
                    float dist = fmaf(-2.0f, dot, nzr[slot] + nec[nt]);
                    if (dist < b1v[slot]) {
                        b2v[slot] = b1v[slot]; b2i[slot] = b1i[slot];
                        b1v[slot] = dist;      b1i[slot] = col;
                    } else if (dist < b2v[slot]) {
                        b2v[slot] = dist; b2i[slot] = col;
                    }
                }
            }
    }

    // cross-lane top-2 merge per row (reuse LDS: buf0 as floats, buf1 as ints)
    float* redv = (float*)Bs;            // [64 rows][32 entries][2]
    int*   redi = (int*)(Bs + 16384);
    #pragma unroll
    for (int mt = 0; mt < 2; ++mt)
        #pragma unroll
        for (int r = 0; r < 4; ++r) {
            int slot = mt * 4 + r;
            int rl = mh + mt * 16 + q * 4 + r;
            int ei = rl * 64 + ((w >> 1) * 16 + cl) * 2;
            redv[ei] = b1v[slot]; redv[ei + 1] = b2v[slot];
            redi[ei] = b1i[slot]; redi[ei + 1] = b2i[slot];
        }
    __syncthreads();
    if (t < TM) {
        float B1v = 3.4e38f, B2v = 3.4e38f; int B1i = 0x7fffffff, B2i = 0x7fffffff;
        for (int j = 0; j < 64; ++j) {
            float v = redv[t * 64 + j]; int ii = redi[t * 64 + j];
            if (v < B1v || (v == B1v && ii < B1i)) { B2v = B1v; B2i = B1i; B1v = v; B1i = ii; }
            else if (v < B2v || (v == B2v && ii < B2i)) { B2v = v; B2i = ii; }
        }
        candL[t] = (unsigned)B1i | ((unsigned)B2i << 16);
    }
    __syncthreads();

    // ---- fused exact fp32 re-rank of top-2 (bitwise-identical to old K2) ---
    // z rows still L2-hot from the A load; e (512 KB) is L2/L3-resident.
    float wsum = 0.0f;
    const int rloc = w * 16;
    for (int i = 0; i < 16; ++i) {
        int row = r0 + rloc + i;
        unsigned pk = candL[rloc + i];
        int c1 = (int)(pk & 0xffffu), c2 = (int)(pk >> 16);
        float2 zv = ((const float2*)(z + (size_t)row * DD))[lane];
        float2 e1 = ((const float2*)(e + (size_t)c1 * DD))[lane];
        float2 e2 = ((const float2*)(e + (size_t)c2 * DD))[lane];
        float v0 = zv.x * zv.x + zv.y * zv.y;   // |z|^2
        float v1 = zv.x * e1.x + zv.y * e1.y;   // z.e1
        float v2 = zv.x * e2.x + zv.y * e2.y;   // z.e2
        float v3 = e1.x * e1.x + e1.y * e1.y;   // |e1|^2
        float v4 = e2.x * e2.x + e2.y * e2.y;   // |e2|^2
        #pragma unroll
        for (int off = 32; off; off >>= 1) {
            v0 += __shfl_down(v0, off, 64);
            v1 += __shfl_down(v1, off, 64);
            v2 += __shfl_down(v2, off, 64);
            v3 += __shfl_down(v3, off, 64);
            v4 += __shfl_down(v4, off, 64);
        }
        int choice = 0; float ssq = 0.0f;
        if (lane == 0) {
            float d1 = fmaf(-2.0f, v1, v0 + v3);
            float d2 = fmaf(-2.0f, v2, v0 + v4);
            choice = (d2 < d1 || (d2 == d1 && c2 < c1)) ? 1 : 0;
            ssq = choice ? d2 : d1;             // = |z - e*|^2
        }
        choice = __shfl(choice, 0, 64);
        float2 es; es.x = choice ? e2.x : e1.x; es.y = choice ? e2.y : e1.y;
        int cs = choice ? c2 : c1;
        ((float2*)(zq + (size_t)row * DD))[lane] = es;
        if (lane == 0) {
            wsum += sqrtf(fmaxf(ssq, 0.0f));
            idsf[row] = (float)cs;
        }
    }
    if (lane == 0) bs[w] = wsum;
    __syncthreads();
    if (t == 0)
        atomicAdd(loss, (bs[0] + bs[1] + bs[2] + bs[3]) * ((1.0f + BETA) / (float)MTOT));
}

// ---------------- launcher --------------------------------------------------
extern "C" void kernel_launch(void* const* d_in, const int* in_sizes, int n_in,
                              void* d_out, int out_size, void* d_ws, size_t ws_size,
                              hipStream_t stream) {
    const float* z = (const float*)d_in[0];
    const float* e = (const float*)d_in[1];
    float* out  = (float*)d_out;
    float* zq   = out;                          // [MTOT*DD]
    float* sim  = out + (size_t)MTOT * DD;      // [MTOT*KK]
    float* idsf = sim + (size_t)MTOT * KK;      // [MTOT]
    float* loss = idsf + MTOT;                  // [1]

    // codebook bf16 hi/lo (pre-swizzled) + norms now live in the workspace:
    // k_main's fused tail writes zq while other blocks still read bpre, so
    // parking in the zq region (as before) would race.
    ushort* bpre = (ushort*)d_ws;               // hi: [0,262144)B, lo: [262144,524288)B
    float*  nef  = (float*)((char*)d_ws + 524288);
    float*  inef = nef + 1024;

    k_norms<<<64,        256, 0, stream>>>(e, bpre, nef, inef, loss);
    k_main <<<MTOT / TM, 256, 0, stream>>>(z, sim, bpre, nef, inef, e, zq, idsf, loss);
}